// Round 9
// baseline (64.241 us; speedup 1.0000x reference)
//
#include <hip/hip_runtime.h>
#include <hip/hip_bf16.h>

// GraphAttentionLayer collapse: out[b,i,o] = (S_mask[b,i,o] < 0) ? 1 : 0,
// S_mask = sum_{adj[i,j]==0} hW[b,j,o]  (|9e15*S_mask| >> |softmax term| => sigmoid saturates).
// Exact i8 MFMA path:
//   q = rint(hW*2^16) = d0 + 256*d1 + 65536*d2, balanced digits in [-128,127] (exact i8).
//   mask bit 0/1 exact i8; i32 MFMA accumulation exact.
//   S = c0 + 256*c1 + 65536*c2 (f64, exact integers). |S| > 2048 => sign reliable;
//   else exact f64 recompute in-block.
// Round-9: pack rebuilt as coalesced-stream + LDS transpose (old pattern gathered
// 16B/lane from 16KB-strided rows -> latency-bound 42us). gemm gets bijective
// XCD swizzle so each XCD's L2 holds ONE batch B-panel (768KB, reused 32x).

#define GN 4096
#define GB 4
#define FIN 128
#define FOUT 64

typedef int i32x4 __attribute__((ext_vector_type(4)));
typedef unsigned int uint32x4 __attribute__((ext_vector_type(4)));
typedef float f32x4 __attribute__((ext_vector_type(4)));

// ---- kernel 1: adj -> transposed bitmask tmask[(rt*64+s)*64 + l] (u64) ----
// bit (r*16+jj) of tmask[(rt*64+s)][l] = (adj[rt*64 + r*16 + (l&15)][s*64 + (l>>4)*16 + jj] == 0)
// Block (rt, cp): reads adj rows rt*64..+64, cols cp*1024..+1024 fully coalesced
// (64B/thread/iter in streaming order), transposes via LDS u16[64][68] (pad: row
// stride 136B -> 16 row16-values hit 16 distinct banks).
__global__ __launch_bounds__(256) void pack_kernel(const int* __restrict__ adj,
                                                   unsigned long long* __restrict__ tmask) {
    __shared__ unsigned short m16[64][68];
    const int t = threadIdx.x;
    const int rt = (int)blockIdx.x >> 2, cp = (int)blockIdx.x & 3;

    // phase 1: row = t>>2, jq = t&3; iter it: j16 = it*4 + jq
    const int row = t >> 2, jq = t & 3;
    const int* rbase = adj + (size_t)(rt * 64 + row) * GN + cp * 1024;
#pragma unroll
    for (int it = 0; it < 16; ++it) {
        const int j16 = it * 4 + jq;
        const i32x4* p = (const i32x4*)(rbase + j16 * 16);
        unsigned int b16 = 0;
#pragma unroll
        for (int q = 0; q < 4; ++q) {
            i32x4 v = p[q];
            b16 |= (v.x == 0 ? 1u : 0u) << (q * 4);
            b16 |= (v.y == 0 ? 2u : 0u) << (q * 4);
            b16 |= (v.z == 0 ? 4u : 0u) << (q * 4);
            b16 |= (v.w == 0 ? 8u : 0u) << (q * 4);
        }
        m16[row][j16] = (unsigned short)b16;
    }
    __syncthreads();

    // phase 2: assemble u64 words. idx -> (sloc, l); s = cp*16 + sloc.
    // res bit (r*16+jj) = bit jj of m16[r*16+row16][sloc*4+g]
    //   = (adj[rt*64+r*16+row16][cp*1024 + sloc*64 + g*16 + jj]==0)   [matches layout]
#pragma unroll
    for (int it = 0; it < 4; ++it) {
        const int idx = it * 256 + t;
        const int sloc = idx >> 6, l = idx & 63;
        const int row16 = l & 15, g = l >> 4;
        unsigned long long res = 0ull;
#pragma unroll
        for (int r = 0; r < 4; ++r)
            res |= (unsigned long long)m16[r * 16 + row16][sloc * 4 + g] << (r * 16);
        tmask[((size_t)rt * 64 + cp * 16 + sloc) * 64 + l] = res;
    }
}

// ---- kernel 2: hW = h @ W (f64) + fused digit-plane packing ----
// Bp[(b*64+p)*12288 + pl*4096 + cg*1024 + g*256 + col16*16 + qr*4] (verified r7/r8).
__global__ __launch_bounds__(256) void hwrepack_kernel(const float* __restrict__ h,
                                                       const float* __restrict__ W,
                                                       double* __restrict__ hW,
                                                       unsigned char* __restrict__ Bp) {
    const int grp = threadIdx.x >> 6;
    const int o = threadIdx.x & 63;
    const int b = (int)blockIdx.x >> 10, q4 = (int)blockIdx.x & 1023;
    __shared__ float hs[4][FIN];
    __shared__ unsigned int dg[4][64];
    {
        const f32x4* src = (const f32x4*)(h + ((size_t)b * GN + q4 * 4) * FIN);
        f32x4* dst = (f32x4*)&hs[0][0];
        if (threadIdx.x < 128) dst[threadIdx.x] = src[threadIdx.x];
    }
    __syncthreads();
    double a0 = 0, a1 = 0, a2 = 0, a3 = 0;
#pragma unroll
    for (int i = 0; i < FIN; i += 4) {
        a0 = fma((double)hs[grp][i],     (double)W[i * FOUT + o],       a0);
        a1 = fma((double)hs[grp][i + 1], (double)W[(i + 1) * FOUT + o], a1);
        a2 = fma((double)hs[grp][i + 2], (double)W[(i + 2) * FOUT + o], a2);
        a3 = fma((double)hs[grp][i + 3], (double)W[(i + 3) * FOUT + o], a3);
    }
    double acc = (a0 + a1) + (a2 + a3);
    hW[((size_t)b * GN + q4 * 4 + grp) * FOUT + o] = acc;

    int qi = (int)llrint(acc * 65536.0);
    int d0 = ((qi + 128) & 255) - 128; qi = (qi - d0) >> 8;
    int d1 = ((qi + 128) & 255) - 128; qi = (qi - d1) >> 8;  // qi now = d2
    dg[grp][o] = (unsigned int)(d0 & 255) | ((unsigned int)(d1 & 255) << 8)
               | ((unsigned int)(qi & 255) << 16);
    __syncthreads();
    if (grp < 3) {   // grp = digit plane
        unsigned int w = 0;
#pragma unroll
        for (int rr = 0; rr < 4; ++rr)
            w |= ((dg[rr][o] >> (grp * 8)) & 255u) << (rr * 8);
        const int p = q4 >> 4, g = (q4 >> 2) & 3, qr = q4 & 3;
        const int cg = o >> 4, col16 = o & 15;
        *(unsigned int*)(Bp + ((size_t)b * 64 + p) * 12288 + grp * 4096
                         + cg * 1024 + g * 256 + col16 * 16 + qr * 4) = w;
    }
}

// ---- kernel 3: exact i8-MFMA masked-sum GEMM + in-block exact fixup ----
// XCD-aware mapping (bijective, 256%8==0): xcd = bid&7 -> batch b = xcd>>1,
// rt = (xcd&1)*32 + bid>>3. Each XCD streams ONE 768KB B-panel (L2-resident, 32x reuse).
__global__ __launch_bounds__(512, 1) void gemm_kernel(const unsigned char* __restrict__ Bp,
                                                      const unsigned long long* __restrict__ tmask,
                                                      const double* __restrict__ hW,
                                                      float* __restrict__ out) {
    __shared__ __align__(16) unsigned char lds[49152];   // kg-merge
    __shared__ unsigned int nflag;
    __shared__ unsigned int flagbuf[128];
    __shared__ double fred[8];

    const int tid = threadIdx.x, lane = tid & 63, wv = tid >> 6;
    const int cg = wv & 3, kg = wv >> 2;
    const int xcd = (int)blockIdx.x & 7, wslot = (int)blockIdx.x >> 3;
    const int b = xcd >> 1, rt = (xcd & 1) * 32 + wslot;
    if (tid == 0) nflag = 0;

    const unsigned char* bptr = Bp + (size_t)b * 786432 + kg * 12288 + cg * 1024 + lane * 16;
    const unsigned long long* mptr = tmask + (size_t)rt * 4096 + kg * 64 + lane;

    i32x4 acc[4][3];
#pragma unroll
    for (int r = 0; r < 4; ++r)
#pragma unroll
        for (int pl = 0; pl < 3; ++pl) {
            i32x4 z = {0, 0, 0, 0};
            acc[r][pl] = z;
        }

    // depth-2 register pipeline
    i32x4 ba0 = *(const i32x4*)(bptr);
    i32x4 ba1 = *(const i32x4*)(bptr + 4096);
    i32x4 ba2 = *(const i32x4*)(bptr + 8192);
    unsigned long long ma = mptr[0];
    i32x4 bb0 = *(const i32x4*)(bptr + 24576);
    i32x4 bb1 = *(const i32x4*)(bptr + 24576 + 4096);
    i32x4 bb2 = *(const i32x4*)(bptr + 24576 + 8192);
    unsigned long long mb = mptr[128];

    auto dostep = [&](unsigned long long mw, i32x4 v0, i32x4 v1, i32x4 v2) {
        const unsigned int mlo = (unsigned int)mw, mhi = (unsigned int)(mw >> 32);
#pragma unroll
        for (int r = 0; r < 4; ++r) {
            unsigned int half = (r >> 1) ? mhi : mlo;
            unsigned int w16 = (r & 1) ? (half >> 16) : (half & 0xFFFFu);
            uint32x4 u;
#pragma unroll
            for (int q = 0; q < 4; ++q)
                u[q] = (((w16 >> (4 * q)) & 0xFu) * 0x00204081u) & 0x01010101u;
            i32x4 af = __builtin_bit_cast(i32x4, u);
            acc[r][0] = __builtin_amdgcn_mfma_i32_16x16x64_i8(af, v0, acc[r][0], 0, 0, 0);
            acc[r][1] = __builtin_amdgcn_mfma_i32_16x16x64_i8(af, v1, acc[r][1], 0, 0, 0);
            acc[r][2] = __builtin_amdgcn_mfma_i32_16x16x64_i8(af, v2, acc[r][2], 0, 0, 0);
        }
    };

    for (int T = 0; T < 32; T += 2) {
        dostep(ma, ba0, ba1, ba2);
        if (T + 2 < 32) {
            const unsigned char* g2 = bptr + (size_t)(T + 2) * 24576;
            ba0 = *(const i32x4*)(g2);
            ba1 = *(const i32x4*)(g2 + 4096);
            ba2 = *(const i32x4*)(g2 + 8192);
            ma = mptr[(size_t)(T + 2) * 128];
        }
        dostep(mb, bb0, bb1, bb2);
        if (T + 3 < 32) {
            const unsigned char* g3 = bptr + (size_t)(T + 3) * 24576;
            bb0 = *(const i32x4*)(g3);
            bb1 = *(const i32x4*)(g3 + 4096);
            bb2 = *(const i32x4*)(g3 + 8192);
            mb = mptr[(size_t)(T + 3) * 128];
        }
    }

    // merge kg=1 partials into kg=0 via LDS
    __syncthreads();
    if (kg == 1) {
        unsigned char* dst = lds + cg * 12288 + lane * 192;
#pragma unroll
        for (int r = 0; r < 4; ++r)
#pragma unroll
            for (int pl = 0; pl < 3; ++pl)
                *(i32x4*)(dst + (r * 3 + pl) * 16) = acc[r][pl];
    }
    __syncthreads();
    if (kg == 0) {
        const unsigned char* s2 = lds + cg * 12288 + lane * 192;
#pragma unroll
        for (int r = 0; r < 4; ++r)
#pragma unroll
            for (int pl = 0; pl < 3; ++pl) {
                i32x4 v = *(const i32x4*)(s2 + (r * 3 + pl) * 16);
#pragma unroll
                for (int q = 0; q < 4; ++q) acc[r][pl][q] += v[q];
            }

        const int o = cg * 16 + (lane & 15);
#pragma unroll
        for (int r = 0; r < 4; ++r) {
#pragma unroll
            for (int q = 0; q < 4; ++q) {
                double S = (double)acc[r][0][q] + 256.0 * (double)acc[r][1][q]
                         + 65536.0 * (double)acc[r][2][q];     // exact integer
                int i = rt * 64 + r * 16 + (lane >> 4) * 4 + q;  // C/D row map (m89)
                size_t oi = ((size_t)b * GN + i) * FOUT + o;
                out[oi] = S < 0.0 ? 1.0f : 0.0f;
                if (fabs(S) <= 2048.0) {
                    unsigned int idx = atomicAdd(&nflag, 1u);
                    if (idx < 128) flagbuf[idx] = ((unsigned int)i << 6) | (unsigned int)o;
                }
            }
        }
    }

    // ---- in-block exact fixup (expected ~0.2 items/block) ----
    __syncthreads();
    unsigned int nf = nflag;
    if (nf > 128) nf = 128;
    for (unsigned int f = 0; f < nf; ++f) {
        unsigned int e = flagbuf[f];
        int o = e & 63;
        int i = (int)(e >> 6);
        int row16 = i & 15, r = (i >> 4) & 3;
        int s = tid >> 3, lg = (tid >> 1) & 3, hf = tid & 1;
        unsigned long long w = tmask[((size_t)rt * 64 + s) * 64 + (lg * 16 + row16)];
        double ps = 0.0;
        const double* hwc = hW + ((size_t)b * GN + s * 64 + lg * 16) * FOUT + o;
#pragma unroll
        for (int jj = hf * 8; jj < hf * 8 + 8; ++jj) {
            if ((w >> (r * 16 + jj)) & 1ull)
                ps += hwc[(size_t)jj * FOUT];
        }
#pragma unroll
        for (int d = 32; d >= 1; d >>= 1) ps += __shfl_down(ps, d, 64);
        if (lane == 0) fred[wv] = ps;
        __syncthreads();
        if (tid == 0) {
            double tot = ((fred[0] + fred[1]) + (fred[2] + fred[3]))
                       + ((fred[4] + fred[5]) + (fred[6] + fred[7]));
            out[((size_t)b * GN + i) * FOUT + o] = tot < 0.0 ? 1.0f : 0.0f;
        }
        __syncthreads();
    }
}

extern "C" void kernel_launch(void* const* d_in, const int* in_sizes, int n_in,
                              void* d_out, int out_size, void* d_ws, size_t ws_size,
                              hipStream_t stream) {
    const float* h   = (const float*)d_in[0];   // [4,4096,128]
    const int*   adj = (const int*)d_in[1];     // [4096,4096]
    const float* W   = (const float*)d_in[2];   // [128,64]
    float* out = (float*)d_out;                 // [4,4096,64] f32

    char* ws = (char*)d_ws;
    double* hW                = (double*)ws;                          // 8 MB @ 0
    unsigned char* Bp         = (unsigned char*)(ws + 8388608);       // 3 MB @ 8M
    unsigned long long* tmask = (unsigned long long*)(ws + 12582912); // 2 MB @ 12M

    pack_kernel<<<256, 256, 0, stream>>>(adj, tmask);
    hwrepack_kernel<<<4096, 256, 0, stream>>>(h, W, hW, Bp);
    gemm_kernel<<<256, 512, 0, stream>>>(Bp, tmask, hW, out);
}

// Round 10
// 57.505 us; speedup vs baseline: 1.1171x; 1.1171x over previous
//
#include <hip/hip_runtime.h>
#include <hip/hip_bf16.h>

// GraphAttentionLayer collapse: out[b,i,o] = (S_mask[b,i,o] < 0) ? 1 : 0,
// S_mask = sum_{adj[i,j]==0} hW[b,j,o]  (|9e15*S_mask| >> |softmax term| => sigmoid saturates).
// Exact i8 MFMA path:
//   q = rint(hW*2^16) = d0 + 256*d1 + 65536*d2, balanced digits in [-128,127] (exact i8).
//   mask bit 0/1 exact i8; i32 MFMA accumulation exact.
//   S = c0 + 256*c1 + 65536*c2 (f64, exact integers). |S| > 2048 => sign reliable;
//   else exact f64 recompute in-block.
// Round-10: re-fuse pack+hwrepack (overlap HBM-bound pack with VALU-bound hwrepack);
// hwrepack stages h as f64 in LDS (2 cvts/thread, was 128); gemm reverts the XCD
// swizzle (R9 regression) and deepens the register pipeline to depth-4 (covers
// L3 cold-miss latency ~700-900cy; depth-2 only covered ~230cy).

#define GN 4096
#define GB 4
#define FIN 128
#define FOUT 64

typedef int i32x4 __attribute__((ext_vector_type(4)));
typedef unsigned int uint32x4 __attribute__((ext_vector_type(4)));
typedef float f32x4 __attribute__((ext_vector_type(4)));
typedef float f32x2 __attribute__((ext_vector_type(2)));

// ---- kernel 1: fused [pack: adj->tmask, blocks 0..255] | [hwrepack, blocks 256..4351] ----
// pack: bit (r*16+jj) of tmask[(rt*64+s)][l] = (adj[rt*64+r*16+(l&15)][s*64+(l>>4)*16+jj]==0).
// Coalesced stream + LDS u16[64][68] transpose (verified R9, absmax 0).
// hwrepack: hW = h@W in f64 + digit planes to Bp (layout verified R7/R8/R9).
__global__ __launch_bounds__(256) void front_kernel(const int* __restrict__ adj,
                                                    const float* __restrict__ h,
                                                    const float* __restrict__ W,
                                                    unsigned long long* __restrict__ tmask,
                                                    double* __restrict__ hW,
                                                    unsigned char* __restrict__ Bp) {
    __shared__ unsigned short m16[64][68];
    __shared__ double hsd[4][FIN];
    __shared__ unsigned int dg[4][64];

    if (blockIdx.x < 256) {
        // ---------------- pack (coalesced + LDS transpose) ----------------
        const int t = threadIdx.x;
        const int rt = (int)blockIdx.x >> 2, cp = (int)blockIdx.x & 3;
        const int row = t >> 2, jq = t & 3;
        const int* rbase = adj + (size_t)(rt * 64 + row) * GN + cp * 1024;
#pragma unroll
        for (int it = 0; it < 16; ++it) {
            const int j16 = it * 4 + jq;
            const i32x4* p = (const i32x4*)(rbase + j16 * 16);
            unsigned int b16 = 0;
#pragma unroll
            for (int q = 0; q < 4; ++q) {
                i32x4 v = p[q];
                b16 |= (v.x == 0 ? 1u : 0u) << (q * 4);
                b16 |= (v.y == 0 ? 2u : 0u) << (q * 4);
                b16 |= (v.z == 0 ? 4u : 0u) << (q * 4);
                b16 |= (v.w == 0 ? 8u : 0u) << (q * 4);
            }
            m16[row][j16] = (unsigned short)b16;
        }
        __syncthreads();
#pragma unroll
        for (int it = 0; it < 4; ++it) {
            const int idx = it * 256 + t;
            const int sloc = idx >> 6, l = idx & 63;
            const int row16 = l & 15, g = l >> 4;
            unsigned long long res = 0ull;
#pragma unroll
            for (int r = 0; r < 4; ++r)
                res |= (unsigned long long)m16[r * 16 + row16][sloc * 4 + g] << (r * 16);
            tmask[((size_t)rt * 64 + cp * 16 + sloc) * 64 + l] = res;
        }
    } else {
        // ---------------- hwrepack ----------------
        const int bx = (int)blockIdx.x - 256;
        const int grp = threadIdx.x >> 6;
        const int o = threadIdx.x & 63;
        const int b = bx >> 10, q4 = bx & 1023;
        {
            // stage 4 rows of h as f64: 2 cvts/thread
            const f32x2* src = (const f32x2*)(h + ((size_t)b * GN + q4 * 4) * FIN);
            f32x2 v = src[threadIdx.x];
            double* drow = &hsd[threadIdx.x >> 6][(threadIdx.x & 63) * 2];
            drow[0] = (double)v.x;
            drow[1] = (double)v.y;
        }
        __syncthreads();
        double a0 = 0, a1 = 0, a2 = 0, a3 = 0;
#pragma unroll
        for (int i = 0; i < FIN; i += 4) {
            a0 = fma(hsd[grp][i],     (double)W[i * FOUT + o],       a0);
            a1 = fma(hsd[grp][i + 1], (double)W[(i + 1) * FOUT + o], a1);
            a2 = fma(hsd[grp][i + 2], (double)W[(i + 2) * FOUT + o], a2);
            a3 = fma(hsd[grp][i + 3], (double)W[(i + 3) * FOUT + o], a3);
        }
        double acc = (a0 + a1) + (a2 + a3);
        hW[((size_t)b * GN + q4 * 4 + grp) * FOUT + o] = acc;

        int qi = (int)llrint(acc * 65536.0);
        int d0 = ((qi + 128) & 255) - 128; qi = (qi - d0) >> 8;
        int d1 = ((qi + 128) & 255) - 128; qi = (qi - d1) >> 8;  // qi now = d2
        dg[grp][o] = (unsigned int)(d0 & 255) | ((unsigned int)(d1 & 255) << 8)
                   | ((unsigned int)(qi & 255) << 16);
        __syncthreads();
        if (grp < 3) {   // grp = digit plane
            unsigned int w = 0;
#pragma unroll
            for (int rr = 0; rr < 4; ++rr)
                w |= ((dg[rr][o] >> (grp * 8)) & 255u) << (rr * 8);
            const int p = q4 >> 4, g = (q4 >> 2) & 3, qr = q4 & 3;
            const int cg = o >> 4, col16 = o & 15;
            *(unsigned int*)(Bp + ((size_t)b * 64 + p) * 12288 + grp * 4096
                             + cg * 1024 + g * 256 + col16 * 16 + qr * 4) = w;
        }
    }
}

// ---- kernel 2: exact i8-MFMA masked-sum GEMM, depth-4 register pipeline ----
// Mapping reverted to R7/R8 (b = bid&3, rt = bid>>2). 8 waves read disjoint B
// slices; no k-loop barriers. Borderline outputs fixed up exactly in-block.
__global__ __launch_bounds__(512, 1) void gemm_kernel(const unsigned char* __restrict__ Bp,
                                                      const unsigned long long* __restrict__ tmask,
                                                      const double* __restrict__ hW,
                                                      float* __restrict__ out) {
    __shared__ __align__(16) unsigned char lds[49152];   // kg-merge
    __shared__ unsigned int nflag;
    __shared__ unsigned int flagbuf[128];
    __shared__ double fred[8];

    const int tid = threadIdx.x, lane = tid & 63, wv = tid >> 6;
    const int cg = wv & 3, kg = wv >> 2;
    const int rt = (int)blockIdx.x >> 2, b = (int)blockIdx.x & 3;
    if (tid == 0) nflag = 0;

    const unsigned char* bptr = Bp + (size_t)b * 786432 + kg * 12288 + cg * 1024 + lane * 16;
    const unsigned long long* mptr = tmask + (size_t)rt * 4096 + kg * 64 + lane;

    i32x4 acc[4][3];
#pragma unroll
    for (int r = 0; r < 4; ++r)
#pragma unroll
        for (int pl = 0; pl < 3; ++pl) {
            i32x4 z = {0, 0, 0, 0};
            acc[r][pl] = z;
        }

#define DECLSET(S) i32x4 b##S##0, b##S##1, b##S##2; unsigned long long m##S;
#define LOADSET(S, T) { const unsigned char* g_ = bptr + (size_t)(T) * 24576;          \
        b##S##0 = *(const i32x4*)(g_);                                                 \
        b##S##1 = *(const i32x4*)(g_ + 4096);                                          \
        b##S##2 = *(const i32x4*)(g_ + 8192);                                          \
        m##S = mptr[(size_t)(T) * 128]; }

    DECLSET(A) DECLSET(B) DECLSET(C) DECLSET(D)
    LOADSET(A, 0) LOADSET(B, 1) LOADSET(C, 2) LOADSET(D, 3)

    auto dostep = [&](unsigned long long mw, i32x4 v0, i32x4 v1, i32x4 v2) {
        const unsigned int mlo = (unsigned int)mw, mhi = (unsigned int)(mw >> 32);
#pragma unroll
        for (int r = 0; r < 4; ++r) {
            unsigned int half = (r >> 1) ? mhi : mlo;
            unsigned int w16 = (r & 1) ? (half >> 16) : (half & 0xFFFFu);
            uint32x4 u;
#pragma unroll
            for (int q = 0; q < 4; ++q)
                u[q] = (((w16 >> (4 * q)) & 0xFu) * 0x00204081u) & 0x01010101u;
            i32x4 af = __builtin_bit_cast(i32x4, u);
            acc[r][0] = __builtin_amdgcn_mfma_i32_16x16x64_i8(af, v0, acc[r][0], 0, 0, 0);
            acc[r][1] = __builtin_amdgcn_mfma_i32_16x16x64_i8(af, v1, acc[r][1], 0, 0, 0);
            acc[r][2] = __builtin_amdgcn_mfma_i32_16x16x64_i8(af, v2, acc[r][2], 0, 0, 0);
        }
    };

    for (int T = 0; T < 32; T += 4) {
        dostep(mA, bA0, bA1, bA2);
        if (T + 4 < 32) LOADSET(A, T + 4)
        dostep(mB, bB0, bB1, bB2);
        if (T + 5 < 32) LOADSET(B, T + 5)
        dostep(mC, bC0, bC1, bC2);
        if (T + 6 < 32) LOADSET(C, T + 6)
        dostep(mD, bD0, bD1, bD2);
        if (T + 7 < 32) LOADSET(D, T + 7)
    }
#undef DECLSET
#undef LOADSET

    // merge kg=1 partials into kg=0 via LDS
    __syncthreads();
    if (kg == 1) {
        unsigned char* dst = lds + cg * 12288 + lane * 192;
#pragma unroll
        for (int r = 0; r < 4; ++r)
#pragma unroll
            for (int pl = 0; pl < 3; ++pl)
                *(i32x4*)(dst + (r * 3 + pl) * 16) = acc[r][pl];
    }
    __syncthreads();
    if (kg == 0) {
        const unsigned char* s2 = lds + cg * 12288 + lane * 192;
#pragma unroll
        for (int r = 0; r < 4; ++r)
#pragma unroll
            for (int pl = 0; pl < 3; ++pl) {
                i32x4 v = *(const i32x4*)(s2 + (r * 3 + pl) * 16);
#pragma unroll
                for (int q = 0; q < 4; ++q) acc[r][pl][q] += v[q];
            }

        const int o = cg * 16 + (lane & 15);
#pragma unroll
        for (int r = 0; r < 4; ++r) {
#pragma unroll
            for (int q = 0; q < 4; ++q) {
                double S = (double)acc[r][0][q] + 256.0 * (double)acc[r][1][q]
                         + 65536.0 * (double)acc[r][2][q];     // exact integer
                int i = rt * 64 + r * 16 + (lane >> 4) * 4 + q;  // C/D row map (m89)
                size_t oi = ((size_t)b * GN + i) * FOUT + o;
                out[oi] = S < 0.0 ? 1.0f : 0.0f;
                if (fabs(S) <= 2048.0) {
                    unsigned int idx = atomicAdd(&nflag, 1u);
                    if (idx < 128) flagbuf[idx] = ((unsigned int)i << 6) | (unsigned int)o;
                }
            }
        }
    }

    // ---- in-block exact fixup (expected ~0.2 items/block) ----
    __syncthreads();
    unsigned int nf = nflag;
    if (nf > 128) nf = 128;
    for (unsigned int f = 0; f < nf; ++f) {
        unsigned int e = flagbuf[f];
        int o = e & 63;
        int i = (int)(e >> 6);
        int row16 = i & 15, r = (i >> 4) & 3;
        int s = tid >> 3, lg = (tid >> 1) & 3, hf = tid & 1;
        unsigned long long w = tmask[((size_t)rt * 64 + s) * 64 + (lg * 16 + row16)];
        double ps = 0.0;
        const double* hwc = hW + ((size_t)b * GN + s * 64 + lg * 16) * FOUT + o;
#pragma unroll
        for (int jj = hf * 8; jj < hf * 8 + 8; ++jj) {
            if ((w >> (r * 16 + jj)) & 1ull)
                ps += hwc[(size_t)jj * FOUT];
        }
#pragma unroll
        for (int d = 32; d >= 1; d >>= 1) ps += __shfl_down(ps, d, 64);
        if (lane == 0) fred[wv] = ps;
        __syncthreads();
        if (tid == 0) {
            double tot = ((fred[0] + fred[1]) + (fred[2] + fred[3]))
                       + ((fred[4] + fred[5]) + (fred[6] + fred[7]));
            out[((size_t)b * GN + i) * FOUT + o] = tot < 0.0 ? 1.0f : 0.0f;
        }
        __syncthreads();
    }
}

extern "C" void kernel_launch(void* const* d_in, const int* in_sizes, int n_in,
                              void* d_out, int out_size, void* d_ws, size_t ws_size,
                              hipStream_t stream) {
    const float* h   = (const float*)d_in[0];   // [4,4096,128]
    const int*   adj = (const int*)d_in[1];     // [4096,4096]
    const float* W   = (const float*)d_in[2];   // [128,64]
    float* out = (float*)d_out;                 // [4,4096,64] f32

    char* ws = (char*)d_ws;
    double* hW                = (double*)ws;                          // 8 MB @ 0
    unsigned char* Bp         = (unsigned char*)(ws + 8388608);       // 3 MB @ 8M
    unsigned long long* tmask = (unsigned long long*)(ws + 12582912); // 2 MB @ 12M

    front_kernel<<<4352, 256, 0, stream>>>(adj, h, W, tmask, hW, Bp);
    gemm_kernel<<<256, 512, 0, stream>>>(Bp, tmask, hW, out);
}